// Round 8
// baseline (174.945 us; speedup 1.0000x reference)
//
#include <hip/hip_runtime.h>
#include <stdint.h>

typedef unsigned int u32;
typedef unsigned long long u64;

#define N8   130560   // (2176/8)*(3840/8)   = 272*480
#define N16  32640    // (2176/16)*(3840/16) = 136*240
#define N32  8160     // (2176/32)*(3840/32) = 68*120
#define NTOT 171360
#define NTOT4 42840   // NTOT/4
#define TOPK 1000
#define NWORDS 16
#define NBINS 512
#define BUCKET_SCALE 85.25f
#define LIST_CAP 2016      // 63*32
#define CPB 32             // candidates ranked per block
#define NB1 42             // k1/k4 blocks; 42*512*2 float4 = 43008 >= NTOT4
#define THR1 512
#define RANK_BLKS 63
#define IOU_BLKS 32        // 32*512 = 16384 >= 16000 tasks
#define IOU_THR 512
#define IOU_TASKS (TOPK * NWORDS)   // 16000
#define NMS_CACHE 256
#define POISON 0xAAAAAAAAu

// R16: kill the contended RMWs (R8 lesson: same-line device RMWs ~O(100ns) each at
// the IF point; k4's 168-wide atomicAdd was the biggest remaining latency chain).
// k1's last-arriver tail now computes DETERMINISTIC per-block base offsets from the
// per-block partial hists (stashed in LDS during the reduce pass), so k4 compacts
// with ZERO global atomics. Same candidate set + exact rank -> bit-identical output.
// RMW populations: k1 arrive 84->42, k4 atomic 168->0, k67 arrive 63->32.
// Still 4 dispatches, zero spins, plain-cached data ops everywhere.

// meta u32 indices
#define MI_IOU  0      // line 0: k67 arrive ctr (zeroed by k1 blk0)
#define MI_ARR  128    // line 1: k1 arrive ctr  (NEVER zeroed; normc+self-reset)
#define MI_B    256    // line 2: threshold bucket   (written once by k1 tail)
#define MI_TOT  257    //         total candidates (capped)
#define MI_BASE 258    //         base[0..41] per-block offsets (same line 2)
#define META_U32 512
#define META_ZERO 128  // k1 blk0 zeroes line 0 only

// workspace layout (bytes)
#define OFF_PART 0                  // u32[42*256] u16-pair packed partial hist
#define OFF_META 43008              // u32[512]
#define OFF_NZ   45056              // u64[16]
#define OFF_LIST 45184              // u64[2016]
#define OFF_MASK 61312              // u64[16*1000] transposed: mask[w*1000+i]

__device__ __forceinline__ u32 ald32(const u32* p) {
  return __hip_atomic_load(p, __ATOMIC_RELAXED, __HIP_MEMORY_SCOPE_AGENT);
}
__device__ __forceinline__ u64 ald64(const u64* p) {
  return __hip_atomic_load(p, __ATOMIC_RELAXED, __HIP_MEMORY_SCOPE_AGENT);
}
__device__ __forceinline__ void ast32(u32* p, u32 v) {
  __hip_atomic_store(p, v, __ATOMIC_RELAXED, __HIP_MEMORY_SCOPE_AGENT);
}
__device__ __forceinline__ void ast64(u64* p, u64 v) {
  __hip_atomic_store(p, v, __ATOMIC_RELAXED, __HIP_MEMORY_SCOPE_AGENT);
}
__device__ __forceinline__ u32 normc(u32 v) {   // tolerate 0xAAAAAAAA poison base
  return v >= 0x80000000u ? v - POISON : v;
}
// true for the LAST arriver; self-resets for the next launch
__device__ __forceinline__ bool arrive_last(u32* p, u32 total) {
  u32 old = __hip_atomic_fetch_add(p, 1u, __ATOMIC_RELAXED, __HIP_MEMORY_SCOPE_AGENT);
  if (normc(old) == total - 1u) { ast32(p, 0u); return true; }
  return false;
}

__device__ __forceinline__ u32 bucket_of(float x) {
  u32 b = (u32)(x * BUCKET_SCALE);
  return b > (NBINS - 1) ? (NBINS - 1) : b;
}

__device__ __forceinline__ float4 load_logit4(int v, const float* s8, const float* s16,
                                              const float* s32) {
  int e = v * 4;
  if (e < N8) return ((const float4*)s8)[v];
  if (e < N8 + N16) return ((const float4*)s16)[v - N8 / 4];
  return ((const float4*)s32)[v - (N8 + N16) / 4];
}

__device__ __forceinline__ bool iou_gt04(float4 a, float4 b) {
#pragma clang fp contract(off)
  float areaA = (a.z - a.x) * (a.w - a.y);
  float areaB = (b.z - b.x) * (b.w - b.y);
  float ltx = fmaxf(a.x, b.x);
  float lty = fmaxf(a.y, b.y);
  float rbx = fminf(a.z, b.z);
  float rby = fminf(a.w, b.w);
  float wx = rbx - ltx; wx = wx > 0.0f ? wx : 0.0f;
  float wy = rby - lty; wy = wy > 0.0f ? wy : 0.0f;
  float inter = wx * wy;
  float un = areaA + areaB - inter;
  un = un > 1e-9f ? un : 1e-9f;
  return (inter / un) > 0.4f;
}

__device__ __forceinline__ u64 valid_word(int w, u32 vcnt) {
  int lo = w * 64;
  if ((int)vcnt >= lo + 64) return ~0ull;
  if ((int)vcnt <= lo) return 0ull;
  return (1ull << (vcnt - (u32)lo)) - 1ull;
}

// K1: 42x512x(2 float4) LDS hist -> sc1 packed partial; last arriver reduces
// (stashing partials in LDS), finds B, computes per-block deterministic base
// offsets, publishes B/TOT/base[] on one never-zeroed line. blk0 zeroes MI_IOU+nz.
__global__ void __launch_bounds__(THR1) k1_hist(
    const float* __restrict__ s8, const float* __restrict__ s16, const float* __restrict__ s32,
    u32* __restrict__ part, u32* meta, u64* __restrict__ nz) {
  __shared__ u32 lh[NBINS];             // 2 KB: histogram
  __shared__ u32 ldsp[NB1 * 256];       // 43 KB: tail partial stash
  __shared__ u32 csum[256];
  __shared__ u32 redlo[THR1], redhi[THR1];
  __shared__ u32 red8[64][8];
  __shared__ u32 base42[NB1 + 1];
  __shared__ u32 sB2;
  __shared__ int sLast;
  const int t = threadIdx.x, blk = blockIdx.x;

  if (t < NBINS) lh[t] = 0;             // THR1 == 512 >= NBINS
  __syncthreads();
  const int v0 = blk * 1024 + t, v1 = v0 + 512;
  if (v0 < NTOT4) {
    float4 x = load_logit4(v0, s8, s16, s32);
    if (x.x > 0.0f) atomicAdd(&lh[bucket_of(x.x)], 1u);
    if (x.y > 0.0f) atomicAdd(&lh[bucket_of(x.y)], 1u);
    if (x.z > 0.0f) atomicAdd(&lh[bucket_of(x.z)], 1u);
    if (x.w > 0.0f) atomicAdd(&lh[bucket_of(x.w)], 1u);
  }
  if (v1 < NTOT4) {
    float4 x = load_logit4(v1, s8, s16, s32);
    if (x.x > 0.0f) atomicAdd(&lh[bucket_of(x.x)], 1u);
    if (x.y > 0.0f) atomicAdd(&lh[bucket_of(x.y)], 1u);
    if (x.z > 0.0f) atomicAdd(&lh[bucket_of(x.z)], 1u);
    if (x.w > 0.0f) atomicAdd(&lh[bucket_of(x.w)], 1u);
  }
  __syncthreads();
  if (t < 256)                          // per-block bin count <= 4096 -> u16 ok
    ast32(&part[blk * 256 + t], lh[2 * t] | (lh[2 * t + 1] << 16));
  if (blk == 0) {
    if (t < META_ZERO) meta[t] = 0;     // line 0 only (MI_IOU); boundary-coherent
    if (t < NWORDS) nz[t] = 0ull;
  }
  __syncthreads();                      // drain sc1 partial stores (vmcnt)
  if (t == 0) sLast = arrive_last(&meta[MI_ARR], NB1) ? 1 : 0;
  __syncthreads();
  if (!sLast) return;

  // ---- tail pass 1: reduce 42 partials, stash in LDS ----
  {
    const u32 b = (u32)(t & 255);
    u32 lo = 0, hi = 0;
    for (int p = t >> 8; p < NB1; p += 2) {   // t<256: even p, t>=256: odd p
      u32 w = ald32(&part[p * 256 + b]);
      ldsp[p * 256 + b] = w;
      lo += w & 0xFFFFu; hi += w >> 16;
    }
    redlo[t] = lo; redhi[t] = hi;
  }
  __syncthreads();
  u32 glo = 0, ghi = 0;
  if (t < 256) {
    glo = redlo[t] + redlo[t + 256];
    ghi = redhi[t] + redhi[t + 256];
    csum[t] = glo + ghi;                 // word t = bins 2t (lo) + 2t+1 (hi)
  }
  __syncthreads();
  for (int off = 1; off < 256; off <<= 1) {   // inclusive suffix scan over words
    u32 add = (t < 256 && t + off < 256) ? csum[t + off] : 0u;
    __syncthreads();
    if (t < 256) csum[t] += add;
    __syncthreads();
  }
  if (t == 0 && csum[0] < TOPK) sB2 = 0u;     // fewer than TOPK positives
  if (t < 256) {
    u32 above = (t < 255) ? csum[t + 1] : 0u;
    if (csum[t] >= TOPK && above < TOPK)      // exactly one thread
      sB2 = (above + ghi >= TOPK) ? (u32)(2 * t + 1) : (u32)(2 * t);
  }
  __syncthreads();
  const u32 B = sB2;

  // ---- tail pass 2: per-block candidate counts at B (from LDS), prefix, publish ----
  {
    const int g = t >> 3, l = t & 7;          // 8 threads per source block
    u32 acc = 0;
    if (g < NB1) {
      const int wB = (int)(B >> 1);
      for (int w = l * 32; w < l * 32 + 32; ++w) {
        if (w < wB) continue;
        u32 pv = ldsp[g * 256 + w];
        u32 c = pv >> 16;                     // hi bin (2w+1) >= B whenever w >= wB
        if (w > wB || !(B & 1u)) c += pv & 0xFFFFu;
        acc += c;
      }
      red8[g][l] = acc;
    }
  }
  __syncthreads();
  if (t == 0) {
    u32 run = 0;
    for (int p = 0; p < NB1; ++p) {
      u32 c = red8[p][0] + red8[p][1] + red8[p][2] + red8[p][3]
            + red8[p][4] + red8[p][5] + red8[p][6] + red8[p][7];
      base42[p] = run; run += c;
    }
    base42[NB1] = run;
    meta[MI_B] = B;                            // plain stores, dedicated line,
    meta[MI_TOT] = run > LIST_CAP ? LIST_CAP : run;   // written only here
  }
  __syncthreads();
  if (t < NB1) meta[MI_BASE + t] = base42[t];
}

// K4: 42x512x(2 float4), SAME element mapping as k1. Deterministic compaction:
// dst = base[blk] + intra-block prefix. ZERO global atomics.
__global__ void __launch_bounds__(THR1) k4_compact(
    const float* __restrict__ s8, const float* __restrict__ s16, const float* __restrict__ s32,
    const u32* __restrict__ meta, u64* __restrict__ list) {
  __shared__ u32 sB, sBase;
  __shared__ u32 cnt64[64];                    // 8 waves x 8 slots
  const int t = threadIdx.x, blk = blockIdx.x;
  const int wave = t >> 6, lane = t & 63;
  if (t == 0) { sB = meta[MI_B]; sBase = meta[MI_BASE + blk]; }
  const int v0 = blk * 1024 + t, v1 = v0 + 512;
  float4 x0 = make_float4(-1.f, -1.f, -1.f, -1.f), x1 = x0;
  if (v0 < NTOT4) x0 = load_logit4(v0, s8, s16, s32);
  if (v1 < NTOT4) x1 = load_logit4(v1, s8, s16, s32);
  __syncthreads();
  const u32 B = sB;
  float c[8] = {x0.x, x0.y, x0.z, x0.w, x1.x, x1.y, x1.z, x1.w};
  u32 win = 0;
#pragma unroll
  for (int j = 0; j < 8; ++j)
    if (c[j] > 0.0f && bucket_of(c[j]) >= B) win |= 1u << j;
  u32 wpos[8];
#pragma unroll
  for (int j = 0; j < 8; ++j) {                // wave-uniform ballots
    u64 bal = __ballot((win >> j) & 1u);
    if (lane == 0) cnt64[wave * 8 + j] = (u32)__popcll(bal);
    wpos[j] = (u32)__popcll(bal & ((1ull << lane) - 1ull));
  }
  __syncthreads();
  if (t == 0) {                                // exclusive prefix over 64 counters
    u32 run = 0;
#pragma unroll
    for (int k = 0; k < 64; ++k) { u32 x = cnt64[k]; cnt64[k] = run; run += x; }
  }
  __syncthreads();
  const u32 base = sBase;
#pragma unroll
  for (int j = 0; j < 8; ++j) {
    if ((win >> j) & 1u) {
      u32 dst = base + cnt64[wave * 8 + j] + wpos[j];
      if (dst < LIST_CAP) {
        u32 idx = (u32)(((j < 4) ? v0 : v1) * 4 + (j & 3));
        list[dst] = ((u64)__float_as_uint(c[j]) << 32) | (u64)(~idx);
      }
    }
  }
}

// K5: 63 blocks: exact rank (8 key-slices per candidate) + decode -> out.
__global__ void __launch_bounds__(256) k5_rank(
    const u32* __restrict__ meta, const u64* __restrict__ list,
    const float* __restrict__ bb8,  const float* __restrict__ kp8,
    const float* __restrict__ bb16, const float* __restrict__ kp16,
    const float* __restrict__ bb32, const float* __restrict__ kp32,
    float* __restrict__ out) {
  __shared__ __align__(16) u64 keys[LIST_CAP];
  __shared__ u32 rpart[256];
  __shared__ u32 sCnt;
  const int t = threadIdx.x, blk = blockIdx.x;
  if (t == 0) sCnt = meta[MI_TOT];             // already capped by k1 tail
  __syncthreads();
  const u32 cnt = sCnt;
  for (int j = t; j < LIST_CAP; j += 256) keys[j] = (j < (int)cnt) ? list[j] : 0ull;
  __syncthreads();
  {
    const int ci = t & 31, sl = t >> 5;        // candidate-in-block, key-slice
    const int c = blk * CPB + ci;
    const int chunk = ((int)cnt + 7) >> 3;
    int lo = sl * chunk; if (lo > (int)cnt) lo = (int)cnt;
    int hi = lo + chunk; if (hi > (int)cnt) hi = (int)cnt;
    u64 my = keys[c];
    int r = 0, j = lo;
    for (; j + 4 <= hi; j += 4)
      r += (keys[j] > my) + (keys[j + 1] > my) + (keys[j + 2] > my) + (keys[j + 3] > my);
    for (; j < hi; ++j) r += (keys[j] > my);
    rpart[t] = (u32)r;
  }
  __syncthreads();
  if (t < CPB) {
    const int c = blk * CPB + t;
    if (c < (int)cnt) {
      int rank = 0;
#pragma unroll
      for (int q = 0; q < 8; ++q) rank += (int)rpart[t + 32 * q];
      if (rank < TOPK) {
        u64 my = keys[c];
        float lx = __uint_as_float((u32)(my >> 32));
        float sc = (float)(1.0 / (1.0 + exp(-(double)lx)));   // f64 sigmoid, round once
        u32 idx = ~((u32)my);
        float4 box;
        float kv[10];
        int p, xq, yq;
        float st;
        const float *bb, *kp;
        if (idx < N8) {
          st = 8.f;  p = (int)idx;              xq = p % 480; yq = p / 480; bb = bb8;  kp = kp8;
        } else if (idx < N8 + N16) {
          st = 16.f; p = (int)idx - N8;         xq = p % 240; yq = p / 240; bb = bb16; kp = kp16;
        } else {
          st = 32.f; p = (int)idx - (N8 + N16); xq = p % 120; yq = p / 120; bb = bb32; kp = kp32;
        }
        float cx = (float)xq * st, cy = (float)yq * st;
        {
#pragma clang fp contract(off)
          float d0 = bb[4 * p + 0] * st;
          float d1 = bb[4 * p + 1] * st;
          float d2 = bb[4 * p + 2] * st;
          float d3 = bb[4 * p + 3] * st;
          box.x = cx - d0; box.y = cy - d1; box.z = cx + d2; box.w = cy + d3;
          for (int q = 0; q < 10; ++q)
            kv[q] = kp[10 * p + q] * st + ((q & 1) ? cy : cx);
        }
        ((float4*)out)[rank] = box;
        out[4000 + rank] = sc;
#pragma unroll
        for (int q = 0; q < 10; ++q) out[5000 + 10 * rank + q] = kv[q];
      }
    } else if (c < TOPK) {        // unfilled rows: zero
      ((float4*)out)[c] = make_float4(0.f, 0.f, 0.f, 0.f);
      out[4000 + c] = 0.f;
#pragma unroll
      for (int q = 0; q < 10; ++q) out[5000 + 10 * c + q] = 0.f;
    }
  }
}

// K67: 32x512: suppression bitmask (sc1 stores) + last-arriver greedy NMS.
__global__ void __launch_bounds__(IOU_THR) k67_iou_nms(
    u32* meta, u64* nzWords, u64* mask, float* out) {
  __shared__ __align__(16) char smem[36864];
  __shared__ int isLast;
  __shared__ u32 sPc[16], sOff17[17];
  __shared__ u64 sRem[NWORDS];
  const int t = threadIdx.x, blk = blockIdx.x;

  float4* boxes = (float4*)smem;
  for (int r = t; r < TOPK; r += IOU_THR) boxes[r] = ((const float4*)out)[r];
  __syncthreads();
  int task = blk * IOU_THR + t;
  if (task < IOU_TASKS) {
    int w = task / 1000;          // 0..15  (wave-mostly-uniform)
    int i = task - w * 1000;      // 0..999 (consecutive per lane -> coalesced)
    float4 a = boxes[i];
    int bse = w * 64;
    int jend = (bse + 64) < TOPK ? (bse + 64) : TOPK;
    u64 bits = 0;
    for (int j = bse; j < jend; ++j)          // boxes[j] wave-broadcast
      if (j > i && iou_gt04(a, boxes[j])) bits |= 1ull << (j - bse);
    ast64(&mask[(u64)w * 1000 + i], bits);    // sc1: visible to the last arriver
    if (bits) atomicOr(&nzWords[i >> 6], 1ull << (i & 63));
  }
  __syncthreads();                // drain sc1 mask stores + atomics (vmcnt)
  if (t == 0)
    isLast = (__hip_atomic_fetch_add(&meta[MI_IOU], 1u, __ATOMIC_RELAXED,
                                     __HIP_MEMORY_SCOPE_AGENT) == (u32)(IOU_BLKS - 1));
  __syncthreads();
  if (!isLast) return;

  // ---- last arriver: exact greedy NMS over nonzero-mask rows only ----
  u32 cc = meta[MI_TOT];
  const u32 vcnt = cc < TOPK ? cc : TOPK;
  u32* rows = (u32*)smem;               // up to 1000 row ids (4 KB)
  u64* cache = (u64*)(smem + 4096);     // NMS_CACHE x 16 u64 (32 KB)
  u64 nzv = 0;
  if (t < NWORDS) {
    nzv = ald64(&nzWords[t]) & valid_word(t, vcnt);
    sPc[t] = (u32)__popcll(nzv);
  }
  __syncthreads();
  if (t == 0) {
    u32 o = 0;
    for (int w = 0; w < NWORDS; ++w) { sOff17[w] = o; o += sPc[w]; }
    sOff17[16] = o;
  }
  __syncthreads();
  if (t < NWORDS) {                     // expand to ascending row list
    u64 m = nzv;
    u32 o = sOff17[t];
    while (m) { int b = __builtin_ctzll(m); m &= m - 1; rows[o++] = (u32)(t * 64 + b); }
  }
  __syncthreads();
  const int S = (int)sOff17[16];
  const int Sc = S < NMS_CACHE ? S : NMS_CACHE;
  for (int idx = t; idx < Sc * NWORDS; idx += IOU_THR) {   // parallel mask prefetch
    int s = idx >> 4, w = idx & 15;
    cache[s * NWORDS + w] = ald64(&mask[(u64)w * 1000 + rows[s]]);
  }
  __syncthreads();
  if (t < 64) {                 // serial greedy chain; lane<16 owns word `lane`
    u64 remv = 0;
    for (int s = 0; s < S; ++s) {
      u32 row = rows[s];
      int c = (int)(row >> 6), b = (int)(row & 63);
      u64 remc = __shfl(remv, c);
      if (!((remc >> b) & 1ull)) {     // row alive -> apply its suppression row
        u64 m = 0;
        if (t < NWORDS)
          m = (s < NMS_CACHE) ? cache[s * NWORDS + t] : ald64(&mask[(u64)t * 1000 + row]);
        remv |= m;
      }
    }
    if (t < NWORDS) sRem[t] = valid_word(t, vcnt) & remv;
  }
  __syncthreads();
  for (int r = t; r < TOPK; r += IOU_THR) {
    if ((sRem[r >> 6] >> (r & 63)) & 1ull) {
      ((float4*)out)[r] = make_float4(0.f, 0.f, 0.f, 0.f);
      out[4000 + r] = 0.f;
#pragma unroll
      for (int q = 0; q < 10; ++q) out[5000 + 10 * r + q] = 0.f;
    }
  }
}

extern "C" void kernel_launch(void* const* d_in, const int* in_sizes, int n_in,
                              void* d_out, int out_size, void* d_ws, size_t ws_size,
                              hipStream_t stream) {
  const float* s8   = (const float*)d_in[1];
  const float* bb8  = (const float*)d_in[2];
  const float* kp8  = (const float*)d_in[3];
  const float* s16  = (const float*)d_in[4];
  const float* bb16 = (const float*)d_in[5];
  const float* kp16 = (const float*)d_in[6];
  const float* s32  = (const float*)d_in[7];
  const float* bb32 = (const float*)d_in[8];
  const float* kp32 = (const float*)d_in[9];

  char* ws = (char*)d_ws;
  u32* part    = (u32*)(ws + OFF_PART);
  u32* meta    = (u32*)(ws + OFF_META);
  u64* nzWords = (u64*)(ws + OFF_NZ);
  u64* list    = (u64*)(ws + OFF_LIST);
  u64* mask    = (u64*)(ws + OFF_MASK);
  float* out   = (float*)d_out;

  k1_hist<<<NB1, THR1, 0, stream>>>(s8, s16, s32, part, meta, nzWords);
  k4_compact<<<NB1, THR1, 0, stream>>>(s8, s16, s32, meta, list);
  k5_rank<<<RANK_BLKS, 256, 0, stream>>>(meta, list, bb8, kp8, bb16, kp16, bb32, kp32, out);
  k67_iou_nms<<<IOU_BLKS, IOU_THR, 0, stream>>>(meta, nzWords, mask, out);
}

// Round 9
// 166.587 us; speedup vs baseline: 1.0502x; 1.0502x over previous
//
#include <hip/hip_runtime.h>
#include <stdint.h>

typedef unsigned int u32;
typedef unsigned long long u64;

#define N8   130560   // (2176/8)*(3840/8)   = 272*480
#define N16  32640    // (2176/16)*(3840/16) = 136*240
#define N32  8160     // (2176/32)*(3840/32) = 68*120
#define NTOT 171360
#define NTOT4 42840   // NTOT/4
#define TOPK 1000
#define NWORDS 16
#define NBINS 512
#define BUCKET_SCALE 85.25f
#define LIST_CAP 2016      // 63*32
#define CPB 32             // candidates ranked per block
#define HIST_BLKS 84       // 84*512 threads = 43008 >= NTOT4
#define HIST_THR 512
#define CMP_BLKS 168       // ceil(NTOT4/256)
#define RANK_BLKS 63
#define IOU_BLKS 63
#define IOU_TASKS (TOPK * NWORDS)   // 16000
#define NMS_CACHE 256

// R17: revert to R15 structure (169.7 best) + replace k1's serialized last-arriver
// tail with REDUNDANT PARALLEL findB in k4 (R14-proven pattern, 8x cheaper at
// NBINS=512: each of 168 blocks reduces the 84 packed partials itself — 86KB of
// plain cached coalesced L2 reads with 4 waves of TLP, then a 256-word LDS scan).
// R16 lessons applied: do NOT halve wave counts (42 fat blocks regressed +5.2us);
// per-block one-shot atomics are cheap (keep k4's single atomicAdd).
// k1 is now a pure histogram kernel: plain stores, no sc1, no arrive counter, no
// poison-dependence. 4 dispatches, zero spins, zero sc1 on the k1->k4 path.

#define MI_CNT 0       // line 0: k4 list-count RMW (zeroed by k1 blk0)
#define MI_IOU 128     // line 1: k67 arrive ctr   (zeroed by k1 blk0)
#define META_U32 256

// workspace layout (bytes)
#define OFF_PART 0                  // u32[84*256] u16-pair packed partial hist
#define OFF_META 86016              // u32[256]
#define OFF_NZ   87040              // u64[16]
#define OFF_LIST 87168              // u64[2016]
#define OFF_MASK 103296             // u64[16*1000] transposed: mask[w*1000+i]

__device__ __forceinline__ u64 ald64(const u64* p) {
  return __hip_atomic_load(p, __ATOMIC_RELAXED, __HIP_MEMORY_SCOPE_AGENT);
}
__device__ __forceinline__ void ast64(u64* p, u64 v) {
  __hip_atomic_store(p, v, __ATOMIC_RELAXED, __HIP_MEMORY_SCOPE_AGENT);
}

__device__ __forceinline__ u32 bucket_of(float x) {
  u32 b = (u32)(x * BUCKET_SCALE);
  return b > (NBINS - 1) ? (NBINS - 1) : b;
}

__device__ __forceinline__ float4 load_logit4(int v, const float* s8, const float* s16,
                                              const float* s32) {
  int e = v * 4;
  if (e < N8) return ((const float4*)s8)[v];
  if (e < N8 + N16) return ((const float4*)s16)[v - N8 / 4];
  return ((const float4*)s32)[v - (N8 + N16) / 4];
}

__device__ __forceinline__ bool iou_gt04(float4 a, float4 b) {
#pragma clang fp contract(off)
  float areaA = (a.z - a.x) * (a.w - a.y);
  float areaB = (b.z - b.x) * (b.w - b.y);
  float ltx = fmaxf(a.x, b.x);
  float lty = fmaxf(a.y, b.y);
  float rbx = fminf(a.z, b.z);
  float rby = fminf(a.w, b.w);
  float wx = rbx - ltx; wx = wx > 0.0f ? wx : 0.0f;
  float wy = rby - lty; wy = wy > 0.0f ? wy : 0.0f;
  float inter = wx * wy;
  float un = areaA + areaB - inter;
  un = un > 1e-9f ? un : 1e-9f;
  return (inter / un) > 0.4f;
}

__device__ __forceinline__ u64 valid_word(int w, u32 vcnt) {
  int lo = w * 64;
  if ((int)vcnt >= lo + 64) return ~0ull;
  if ((int)vcnt <= lo) return 0ull;
  return (1ull << (vcnt - (u32)lo)) - 1ull;
}

// K1: pure histogram. 84x512, LDS 512-bin hist -> u16-packed partial (PLAIN
// stores; dispatch boundary provides coherence). blk0 zeroes meta + nz.
__global__ void __launch_bounds__(HIST_THR) k1_hist(
    const float* __restrict__ s8, const float* __restrict__ s16, const float* __restrict__ s32,
    u32* __restrict__ part, u32* __restrict__ meta, u64* __restrict__ nz) {
  __shared__ u32 lh[NBINS];
  const int t = threadIdx.x, blk = blockIdx.x;
  if (t < NBINS) lh[t] = 0;       // HIST_THR == 512 == NBINS
  __syncthreads();
  int v = blk * HIST_THR + t;
  if (v < NTOT4) {
    float4 x = load_logit4(v, s8, s16, s32);
    if (x.x > 0.0f) atomicAdd(&lh[bucket_of(x.x)], 1u);
    if (x.y > 0.0f) atomicAdd(&lh[bucket_of(x.y)], 1u);
    if (x.z > 0.0f) atomicAdd(&lh[bucket_of(x.z)], 1u);
    if (x.w > 0.0f) atomicAdd(&lh[bucket_of(x.w)], 1u);
  }
  __syncthreads();
  if (t < 256)                    // per-block bin count <= 2048 -> u16 ok
    part[blk * 256 + t] = lh[2 * t] | (lh[2 * t + 1] << 16);
  if (blk == 0) {
    if (t < META_U32) meta[t] = 0;
    if (t < NWORDS) nz[t] = 0ull;
  }
}

// K4: every block: redundant parallel findB (reduce 84 partials + 256-word scan)
// then block-aggregated compaction. Plain cached loads; one atomicAdd per block.
__global__ void __launch_bounds__(256) k4_compact(
    const float* __restrict__ s8, const float* __restrict__ s16, const float* __restrict__ s32,
    const u32* __restrict__ part, u32* __restrict__ meta, u64* __restrict__ list) {
  __shared__ u32 csum[256];
  __shared__ u32 sB, sBase;
  __shared__ u32 cnt16[16];
  const int t = threadIdx.x, blk = blockIdx.x;
  const int wave = t >> 6, lane = t & 63;
  const int v = blk * 256 + t;
  // prefetch scores early (latency overlap with the reduce below)
  float4 x = make_float4(-1.f, -1.f, -1.f, -1.f);
  if (v < NTOT4) x = load_logit4(v, s8, s16, s32);

  // ---- redundant findB: thread t owns packed word t (bins 2t, 2t+1) ----
  u32 lo = 0, hi = 0;
  {
    int p = 0;
    for (; p + 4 <= HIST_BLKS; p += 4) {    // coalesced across threads at each p
      u32 a0 = part[(p + 0) * 256 + t];
      u32 a1 = part[(p + 1) * 256 + t];
      u32 a2 = part[(p + 2) * 256 + t];
      u32 a3 = part[(p + 3) * 256 + t];
      lo += (a0 & 0xFFFFu) + (a1 & 0xFFFFu) + (a2 & 0xFFFFu) + (a3 & 0xFFFFu);
      hi += (a0 >> 16) + (a1 >> 16) + (a2 >> 16) + (a3 >> 16);
    }
    for (; p < HIST_BLKS; ++p) {
      u32 a = part[p * 256 + t];
      lo += a & 0xFFFFu; hi += a >> 16;
    }
  }
  csum[t] = lo + hi;
  __syncthreads();
  for (int off = 1; off < 256; off <<= 1) {   // inclusive suffix scan over words
    u32 add = (t + off < 256) ? csum[t + off] : 0u;
    __syncthreads();
    csum[t] += add;
    __syncthreads();
  }
  u32 above = (t < 255) ? csum[t + 1] : 0u;
  if (t == 0 && csum[0] < TOPK) sB = 0u;      // fewer than TOPK positives
  if (csum[t] >= TOPK && above < TOPK)        // exactly one thread
    sB = (above + hi >= TOPK) ? (u32)(2 * t + 1) : (u32)(2 * t);
  __syncthreads();

  // ---- compact ----
  const u32 B = sB;
  float c[4] = {x.x, x.y, x.z, x.w};
  u32 win = 0;
#pragma unroll
  for (int j = 0; j < 4; ++j)
    if (c[j] > 0.0f && bucket_of(c[j]) >= B) win |= 1u << j;
  u32 wpos[4], wcnt[4];
#pragma unroll
  for (int j = 0; j < 4; ++j) {               // wave-uniform ballots
    u64 bal = __ballot((win >> j) & 1u);
    wcnt[j] = (u32)__popcll(bal);
    wpos[j] = (u32)__popcll(bal & ((1ull << lane) - 1ull));
  }
  if (lane == 0) {
#pragma unroll
    for (int j = 0; j < 4; ++j) cnt16[wave * 4 + j] = wcnt[j];
  }
  __syncthreads();
  if (t == 0) {                               // ONE device-atomic RMW per block
    u32 tot = 0, pre[16];
#pragma unroll
    for (int k = 0; k < 16; ++k) { pre[k] = tot; tot += cnt16[k]; }
#pragma unroll
    for (int k = 0; k < 16; ++k) cnt16[k] = pre[k];
    sBase = tot ? atomicAdd(&meta[MI_CNT], tot) : 0u;
  }
  __syncthreads();
#pragma unroll
  for (int j = 0; j < 4; ++j) {
    if ((win >> j) & 1u) {
      u32 dst = sBase + cnt16[wave * 4 + j] + wpos[j];
      if (dst < LIST_CAP) {
        u32 idx = (u32)(v * 4 + j);
        list[dst] = ((u64)__float_as_uint(c[j]) << 32) | (u64)(~idx);
      }
    }
  }
}

// K5: 63 blocks: exact rank (8 key-slices per candidate) + decode -> out.
__global__ void __launch_bounds__(256) k5_rank(
    const u32* __restrict__ meta, const u64* __restrict__ list,
    const float* __restrict__ bb8,  const float* __restrict__ kp8,
    const float* __restrict__ bb16, const float* __restrict__ kp16,
    const float* __restrict__ bb32, const float* __restrict__ kp32,
    float* __restrict__ out) {
  __shared__ __align__(16) u64 keys[LIST_CAP];
  __shared__ u32 rpart[256];
  __shared__ u32 sCnt;
  const int t = threadIdx.x, blk = blockIdx.x;
  if (t == 0) { u32 cc = meta[MI_CNT]; sCnt = cc > LIST_CAP ? LIST_CAP : cc; }
  __syncthreads();
  const u32 cnt = sCnt;
  for (int j = t; j < LIST_CAP; j += 256) keys[j] = (j < (int)cnt) ? list[j] : 0ull;
  __syncthreads();
  {
    const int ci = t & 31, sl = t >> 5;       // candidate-in-block, key-slice
    const int c = blk * CPB + ci;
    const int chunk = ((int)cnt + 7) >> 3;
    int lo = sl * chunk; if (lo > (int)cnt) lo = (int)cnt;
    int hi = lo + chunk; if (hi > (int)cnt) hi = (int)cnt;
    u64 my = keys[c];
    int r = 0, j = lo;
    for (; j + 4 <= hi; j += 4)
      r += (keys[j] > my) + (keys[j + 1] > my) + (keys[j + 2] > my) + (keys[j + 3] > my);
    for (; j < hi; ++j) r += (keys[j] > my);
    rpart[t] = (u32)r;
  }
  __syncthreads();
  if (t < CPB) {
    const int c = blk * CPB + t;
    if (c < (int)cnt) {
      int rank = 0;
#pragma unroll
      for (int q = 0; q < 8; ++q) rank += (int)rpart[t + 32 * q];
      if (rank < TOPK) {
        u64 my = keys[c];
        float lx = __uint_as_float((u32)(my >> 32));
        float sc = (float)(1.0 / (1.0 + exp(-(double)lx)));   // f64 sigmoid, round once
        u32 idx = ~((u32)my);
        float4 box;
        float kv[10];
        int p, xq, yq;
        float st;
        const float *bb, *kp;
        if (idx < N8) {
          st = 8.f;  p = (int)idx;              xq = p % 480; yq = p / 480; bb = bb8;  kp = kp8;
        } else if (idx < N8 + N16) {
          st = 16.f; p = (int)idx - N8;         xq = p % 240; yq = p / 240; bb = bb16; kp = kp16;
        } else {
          st = 32.f; p = (int)idx - (N8 + N16); xq = p % 120; yq = p / 120; bb = bb32; kp = kp32;
        }
        float cx = (float)xq * st, cy = (float)yq * st;
        {
#pragma clang fp contract(off)
          float d0 = bb[4 * p + 0] * st;
          float d1 = bb[4 * p + 1] * st;
          float d2 = bb[4 * p + 2] * st;
          float d3 = bb[4 * p + 3] * st;
          box.x = cx - d0; box.y = cy - d1; box.z = cx + d2; box.w = cy + d3;
          for (int q = 0; q < 10; ++q)
            kv[q] = kp[10 * p + q] * st + ((q & 1) ? cy : cx);
        }
        ((float4*)out)[rank] = box;
        out[4000 + rank] = sc;
#pragma unroll
        for (int q = 0; q < 10; ++q) out[5000 + 10 * rank + q] = kv[q];
      }
    } else if (c < TOPK) {        // unfilled rows: zero
      ((float4*)out)[c] = make_float4(0.f, 0.f, 0.f, 0.f);
      out[4000 + c] = 0.f;
#pragma unroll
      for (int q = 0; q < 10; ++q) out[5000 + 10 * c + q] = 0.f;
    }
  }
}

// K67: suppression bitmask (63 blocks, sc1 stores) + last-arriver greedy NMS.
__global__ void __launch_bounds__(256) k67_iou_nms(
    u32* meta, u64* nzWords, u64* mask, float* out) {
  __shared__ __align__(16) char smem[36864];
  __shared__ int isLast;
  __shared__ u32 sPc[16], sOff17[17];
  __shared__ u64 sRem[NWORDS];
  const int t = threadIdx.x, blk = blockIdx.x;

  float4* boxes = (float4*)smem;
  for (int r = t; r < TOPK; r += 256) boxes[r] = ((const float4*)out)[r];
  __syncthreads();
  int task = blk * 256 + t;
  if (task < IOU_TASKS) {
    int w = task / 1000;          // 0..15  (wave-mostly-uniform)
    int i = task - w * 1000;      // 0..999 (consecutive per lane -> coalesced)
    float4 a = boxes[i];
    int bse = w * 64;
    int jend = (bse + 64) < TOPK ? (bse + 64) : TOPK;
    u64 bits = 0;
    for (int j = bse; j < jend; ++j)          // boxes[j] wave-broadcast
      if (j > i && iou_gt04(a, boxes[j])) bits |= 1ull << (j - bse);
    ast64(&mask[(u64)w * 1000 + i], bits);    // sc1: visible to the last arriver
    if (bits) atomicOr(&nzWords[i >> 6], 1ull << (i & 63));
  }
  __syncthreads();                // drain sc1 mask stores + atomics (vmcnt)
  if (t == 0)
    isLast = (__hip_atomic_fetch_add(&meta[MI_IOU], 1u, __ATOMIC_RELAXED,
                                     __HIP_MEMORY_SCOPE_AGENT) == (u32)(IOU_BLKS - 1));
  __syncthreads();
  if (!isLast) return;

  // ---- last arriver: exact greedy NMS over nonzero-mask rows only ----
  u32 cc = meta[MI_CNT];
  if (cc > LIST_CAP) cc = LIST_CAP;
  const u32 vcnt = cc < TOPK ? cc : TOPK;
  u32* rows = (u32*)smem;               // up to 1000 row ids (4 KB)
  u64* cache = (u64*)(smem + 4096);     // NMS_CACHE x 16 u64 (32 KB)
  u64 nzv = 0;
  if (t < NWORDS) {
    nzv = ald64(&nzWords[t]) & valid_word(t, vcnt);
    sPc[t] = (u32)__popcll(nzv);
  }
  __syncthreads();
  if (t == 0) {
    u32 o = 0;
    for (int w = 0; w < NWORDS; ++w) { sOff17[w] = o; o += sPc[w]; }
    sOff17[16] = o;
  }
  __syncthreads();
  if (t < NWORDS) {                     // expand to ascending row list
    u64 m = nzv;
    u32 o = sOff17[t];
    while (m) { int b = __builtin_ctzll(m); m &= m - 1; rows[o++] = (u32)(t * 64 + b); }
  }
  __syncthreads();
  const int S = (int)sOff17[16];
  const int Sc = S < NMS_CACHE ? S : NMS_CACHE;
  for (int idx = t; idx < Sc * NWORDS; idx += 256) {   // parallel mask prefetch
    int s = idx >> 4, w = idx & 15;
    cache[s * NWORDS + w] = ald64(&mask[(u64)w * 1000 + rows[s]]);
  }
  __syncthreads();
  if (t < 64) {                 // serial greedy chain; lane<16 owns word `lane`
    u64 remv = 0;
    for (int s = 0; s < S; ++s) {
      u32 row = rows[s];
      int c = (int)(row >> 6), b = (int)(row & 63);
      u64 remc = __shfl(remv, c);
      if (!((remc >> b) & 1ull)) {     // row alive -> apply its suppression row
        u64 m = 0;
        if (t < NWORDS)
          m = (s < NMS_CACHE) ? cache[s * NWORDS + t] : ald64(&mask[(u64)t * 1000 + row]);
        remv |= m;
      }
    }
    if (t < NWORDS) sRem[t] = valid_word(t, vcnt) & remv;
  }
  __syncthreads();
  for (int r = t; r < TOPK; r += 256) {
    if ((sRem[r >> 6] >> (r & 63)) & 1ull) {
      ((float4*)out)[r] = make_float4(0.f, 0.f, 0.f, 0.f);
      out[4000 + r] = 0.f;
#pragma unroll
      for (int q = 0; q < 10; ++q) out[5000 + 10 * r + q] = 0.f;
    }
  }
}

extern "C" void kernel_launch(void* const* d_in, const int* in_sizes, int n_in,
                              void* d_out, int out_size, void* d_ws, size_t ws_size,
                              hipStream_t stream) {
  const float* s8   = (const float*)d_in[1];
  const float* bb8  = (const float*)d_in[2];
  const float* kp8  = (const float*)d_in[3];
  const float* s16  = (const float*)d_in[4];
  const float* bb16 = (const float*)d_in[5];
  const float* kp16 = (const float*)d_in[6];
  const float* s32  = (const float*)d_in[7];
  const float* bb32 = (const float*)d_in[8];
  const float* kp32 = (const float*)d_in[9];

  char* ws = (char*)d_ws;
  u32* part    = (u32*)(ws + OFF_PART);
  u32* meta    = (u32*)(ws + OFF_META);
  u64* nzWords = (u64*)(ws + OFF_NZ);
  u64* list    = (u64*)(ws + OFF_LIST);
  u64* mask    = (u64*)(ws + OFF_MASK);
  float* out   = (float*)d_out;

  k1_hist<<<HIST_BLKS, HIST_THR, 0, stream>>>(s8, s16, s32, part, meta, nzWords);
  k4_compact<<<CMP_BLKS, 256, 0, stream>>>(s8, s16, s32, part, meta, list);
  k5_rank<<<RANK_BLKS, 256, 0, stream>>>(meta, list, bb8, kp8, bb16, kp16, bb32, kp32, out);
  k67_iou_nms<<<IOU_BLKS, 256, 0, stream>>>(meta, nzWords, mask, out);
}